// Round 1
// baseline (3619.204 us; speedup 1.0000x reference)
//
#include <hip/hip_runtime.h>
#include <math.h>
#include <stdint.h>

#define L_DIM 1024
#define C_DIM 128
#define H_DIM 512
#define B_DIM 16
#define LC (L_DIM * C_DIM)      // 131072
#define BLC (B_DIM * LC)        // 2097152
#define M_DIM (B_DIM * L_DIM)   // 16384

// ---------------- monotone float -> uint (order-preserving) ----------------
__device__ __forceinline__ unsigned ford(float x) {
    unsigned u = __float_as_uint(x);
    return (u & 0x80000000u) ? ~u : (u | 0x80000000u);
}

// ---------------- tiled fp32 GEMM, C = fuse(A@B + bias [+ t*tw]) -----------
// A: [M,K] row-major, B: [K,N] row-major. M%64==0, N%64==0, K%16==0.
// FUSE==1: gelu(x + bias[n] + t_feat*tw[n]) (tanh approx, JAX default)
// FUSE==0: x + bias[n]
template <int FUSE>
__global__ __launch_bounds__(256) void gemm_kernel(
    const float* __restrict__ A, const float* __restrict__ B,
    const float* __restrict__ bias, const float* __restrict__ tw,
    float t_feat, float* __restrict__ C, int M, int N, int K) {
    __shared__ float As[16][68];  // [k][m], padded
    __shared__ float Bs[16][68];  // [k][n], padded
    const int tid = threadIdx.x;
    const int tx = tid & 15;
    const int ty = tid >> 4;
    const int m0 = blockIdx.y * 64;
    const int n0 = blockIdx.x * 64;

    const int la_row = tid >> 2;         // 0..63
    const int la_k = (tid & 3) << 2;     // 0,4,8,12
    const int lb_row = tid >> 4;         // 0..15
    const int lb_col = (tid & 15) << 2;  // 0..60

    float acc[4][4] = {};

    for (int k0 = 0; k0 < K; k0 += 16) {
        float4 a4 = *(const float4*)(A + (size_t)(m0 + la_row) * K + (k0 + la_k));
        float4 b4 = *(const float4*)(B + (size_t)(k0 + lb_row) * N + (n0 + lb_col));
        __syncthreads();  // previous tile's compute done before overwrite
        As[la_k + 0][la_row] = a4.x;
        As[la_k + 1][la_row] = a4.y;
        As[la_k + 2][la_row] = a4.z;
        As[la_k + 3][la_row] = a4.w;
        *(float4*)(&Bs[lb_row][lb_col]) = b4;
        __syncthreads();
#pragma unroll
        for (int kk = 0; kk < 16; ++kk) {
            float4 av = *(const float4*)(&As[kk][ty << 2]);
            float4 bv = *(const float4*)(&Bs[kk][tx << 2]);
            acc[0][0] += av.x * bv.x; acc[0][1] += av.x * bv.y;
            acc[0][2] += av.x * bv.z; acc[0][3] += av.x * bv.w;
            acc[1][0] += av.y * bv.x; acc[1][1] += av.y * bv.y;
            acc[1][2] += av.y * bv.z; acc[1][3] += av.y * bv.w;
            acc[2][0] += av.z * bv.x; acc[2][1] += av.z * bv.y;
            acc[2][2] += av.z * bv.z; acc[2][3] += av.z * bv.w;
            acc[3][0] += av.w * bv.x; acc[3][1] += av.w * bv.y;
            acc[3][2] += av.w * bv.z; acc[3][3] += av.w * bv.w;
        }
    }

#pragma unroll
    for (int i = 0; i < 4; ++i) {
        const int m = m0 + (ty << 2) + i;
        float o[4];
#pragma unroll
        for (int j = 0; j < 4; ++j) {
            const int n = n0 + (tx << 2) + j;
            float v = acc[i][j] + bias[n];
            if (FUSE) {
                v += t_feat * tw[n];
                float inner = 0.7978845608028654f * (v + 0.044715f * v * v * v);
                v = 0.5f * v * (1.0f + tanhf(inner));
            }
            o[j] = v;
        }
        *(float4*)(C + (size_t)m * N + n0 + (tx << 2)) =
            make_float4(o[0], o[1], o[2], o[3]);
    }
}

// ---------------- ent_pix + var(obs_err) stats -----------------------------
__global__ __launch_bounds__(256) void entvar_kernel(
    const float* __restrict__ eps, const float* __restrict__ z,
    const float* __restrict__ y, const float* __restrict__ mk,
    float* __restrict__ ent, float* __restrict__ accum) {
    const int p = blockIdx.x * 256 + threadIdx.x;  // pixel index < LC
    float sa = 0.f, s1 = 0.f, s2 = 0.f;
#pragma unroll
    for (int b = 0; b < B_DIM; ++b) {
        const size_t i = (size_t)b * LC + p;
        sa += fabsf(eps[i]);
        const float oe = (z[i] - y[i]) * mk[i];
        s1 += oe;
        s2 += oe * oe;
    }
    ent[p] = sa * (1.0f / 16.0f);
    // wave reduce (64 lanes)
    for (int off = 32; off; off >>= 1) {
        s1 += __shfl_down(s1, off);
        s2 += __shfl_down(s2, off);
    }
    __shared__ float r1[4], r2[4];
    const int w = threadIdx.x >> 6, lane = threadIdx.x & 63;
    if (lane == 0) { r1[w] = s1; r2[w] = s2; }
    __syncthreads();
    if (threadIdx.x == 0) {
        atomicAdd(&accum[0], r1[0] + r1[1] + r1[2] + r1[3]);
        atomicAdd(&accum[1], r2[0] + r2[1] + r2[2] + r2[3]);
    }
}

// ---------------- multiscale pooling (w = 2,4,8 from ent) ------------------
__global__ __launch_bounds__(256) void pool_kernel(
    const float* __restrict__ ent, float* __restrict__ p1,
    float* __restrict__ p2, float* __restrict__ p3) {
    const int idx = blockIdx.x * 256 + threadIdx.x;  // < 43008
    if (idx < 32768) {  // w=2: 512 x 64
        const int r = idx >> 6, c = idx & 63;
        float s = 0.f;
#pragma unroll
        for (int i = 0; i < 2; ++i)
#pragma unroll
            for (int j = 0; j < 2; ++j) s += ent[((r * 2 + i) << 7) + c * 2 + j];
        p1[idx] = s * 0.25f;
    } else if (idx < 40960) {  // w=4: 256 x 32
        const int t = idx - 32768;
        const int r = t >> 5, c = t & 31;
        float s = 0.f;
#pragma unroll
        for (int i = 0; i < 4; ++i)
#pragma unroll
            for (int j = 0; j < 4; ++j) s += ent[((r * 4 + i) << 7) + c * 4 + j];
        p2[t] = s * 0.0625f;
    } else {  // w=8: 128 x 16
        const int t = idx - 40960;
        const int r = t >> 4, c = t & 15;
        float s = 0.f;
#pragma unroll
        for (int i = 0; i < 8; ++i)
#pragma unroll
            for (int j = 0; j < 8; ++j) s += ent[((r * 8 + i) << 7) + c * 8 + j];
        p3[t] = s * (1.0f / 64.0f);
    }
}

// ---------------- per-scale exact K-th largest via radix select ------------
// blockIdx.x = scale (0: ent 131072/K26214, 1: 32768/6553, 2: 8192/1638, 3: 2048/409)
__global__ __launch_bounds__(1024) void select_kernel(
    const float* __restrict__ e0, const float* __restrict__ e1,
    const float* __restrict__ e2, const float* __restrict__ e3,
    unsigned* __restrict__ thr) {
    const float* data;
    int n;
    unsigned K;
    switch (blockIdx.x) {
        case 0: data = e0; n = 131072; K = 26214u; break;
        case 1: data = e1; n = 32768; K = 6553u; break;
        case 2: data = e2; n = 8192; K = 1638u; break;
        default: data = e3; n = 2048; K = 409u; break;
    }
    __shared__ unsigned hist[256];
    __shared__ unsigned sh_prefix, sh_krem;
    if (threadIdx.x == 0) { sh_prefix = 0u; sh_krem = K; }
    const int lane = threadIdx.x & 63;
    __syncthreads();

    for (int shift = 24; shift >= 0; shift -= 8) {
        if (threadIdx.x < 256) hist[threadIdx.x] = 0u;
        __syncthreads();
        const unsigned prefix = sh_prefix;
        const unsigned hmask = (shift == 24) ? 0u : (0xFFFFFFFFu << (shift + 8));
        // n is a multiple of 1024 for every scale -> uniform trip count per wave
        for (int i = threadIdx.x; i < n; i += 1024) {
            const unsigned u = ford(data[i]);
            const bool valid = ((u & hmask) == (prefix & hmask));
            const unsigned digit = (u >> shift) & 255u;
            // wave-aggregated histogram atomics (exponent byte is near-constant
            // in pass 0 -> plain atomics would serialize the whole block)
            unsigned long long active = __ballot(valid);
            while (active) {
                const int leader = __ffsll((unsigned long long)active) - 1;
                const unsigned dl = (unsigned)__shfl((int)digit, leader);
                unsigned long long match =
                    __ballot(valid && (digit == dl)) & active;
                if (lane == leader)
                    atomicAdd(&hist[dl], (unsigned)__popcll(match));
                active &= ~match;
            }
        }
        __syncthreads();
        if (threadIdx.x == 0) {
            unsigned k = sh_krem;
            int b = 255;
            for (; b >= 0; --b) {
                const unsigned c = hist[b];
                if (k <= c) break;
                k -= c;
            }
            if (b < 0) b = 0;  // defensive; shouldn't happen
            sh_prefix = prefix | ((unsigned)b << shift);
            sh_krem = k;
        }
        __syncthreads();
    }
    if (threadIdx.x == 0) thr[blockIdx.x] = sh_prefix;
}

// ---------------- fused update: guidance + scale-select + DPM step ---------
__global__ __launch_bounds__(256) void update_kernel(
    float* __restrict__ z, const float* __restrict__ y,
    const float* __restrict__ mk, const float* __restrict__ eps,
    const float* __restrict__ ent, const float* __restrict__ p1,
    const float* __restrict__ p2, const float* __restrict__ p3,
    const unsigned* __restrict__ thr, const float* __restrict__ accum,
    float base_a, float base_b, float h_lam) {
    const int idx = blockIdx.x * 256 + threadIdx.x;  // < BLC
    const int p = idx & (LC - 1);
    const int l = p >> 7;
    const int c = p & 127;

    const float mean = accum[0] * (1.0f / (float)BLC);
    const float var = accum[1] * (1.0f / (float)BLC) - mean * mean;

    const float zi = z[idx];
    const float oe = (zi - y[idx]) * mk[idx];
    const float guid = -oe / (var + 1e-8f);
    const float ei = eps[idx];

    // finest selected scale wins (coarse->fine overwrite in reference)
    float ent_v = 0.f;
    bool sel = false;
    {
        const float v0 = ent[p];
        if (ford(v0) >= thr[0]) { ent_v = v0; sel = true; }
        else {
            const float v1 = p1[((l >> 1) << 6) + (c >> 1)];
            if (ford(v1) >= thr[1]) { ent_v = v1; sel = true; }
            else {
                const float v2 = p2[((l >> 2) << 5) + (c >> 2)];
                if (ford(v2) >= thr[2]) { ent_v = v2; sel = true; }
                else {
                    const float v3 = p3[((l >> 3) << 4) + (c >> 3)];
                    if (ford(v3) >= thr[3]) { ent_v = v3; sel = true; }
                }
            }
        }
    }
    if (sel) {
        // order = 1 + (ent>0.1) + (ent>0.5); corr per Taylor expansion
        float corr;
        if (ent_v > 0.5f)
            corr = 1.0f + h_lam + h_lam * h_lam * (1.0f / 3.0f);
        else if (ent_v > 0.1f)
            corr = 1.0f + 0.5f * h_lam;
        else
            corr = 1.0f;
        const float gs = 2.0f * ent_v / (ent_v + 1.0f);
        z[idx] = base_a * zi - base_b * (corr * ei) + gs * guid;
    }
}

// ---------------------------------------------------------------------------
extern "C" void kernel_launch(void* const* d_in, const int* in_sizes, int n_in,
                              void* d_out, int out_size, void* d_ws,
                              size_t ws_size, hipStream_t stream) {
    const float* y_obs = (const float*)d_in[0];
    const float* mask = (const float*)d_in[1];
    const float* z_init = (const float*)d_in[2];
    const float* W1 = (const float*)d_in[3];
    const float* b1 = (const float*)d_in[4];
    const float* W2 = (const float*)d_in[5];
    const float* b2 = (const float*)d_in[6];
    const float* tw = (const float*)d_in[7];
    float* z = (float*)d_out;
    float* ws = (float*)d_ws;

    // workspace layout (floats)
    float* h = ws;                       // 16384*512 = 8388608
    float* eps = ws + 8388608;           // 2097152
    float* ent = ws + 10485760;          // 131072
    float* p1 = ws + 10616832;           // 32768
    float* p2 = ws + 10649600;           // 8192
    float* p3 = ws + 10657792;           // 2048
    unsigned* thr = (unsigned*)(ws + 10659840);  // 4
    float* accum = ws + 10659856;                // 2

    // diffusion schedule in fp32 (matches jnp fp32 cumprod semantics);
    // input-independent -> safe to bake into captured kernel args
    float alpha_[1000], sigma_[1000], lam_[1000];
    {
        float ac = 1.0f;
        for (int i = 0; i < 1000; ++i) {
            const float beta =
                1e-4f + (0.02f - 1e-4f) * ((float)i / 999.0f);
            ac = ac * (1.0f - beta);
            alpha_[i] = sqrtf(ac);
            sigma_[i] = sqrtf(1.0f - ac);
            lam_[i] = logf(alpha_[i]) - logf(sigma_[i]);
        }
    }

    hipMemcpyAsync(z, z_init, sizeof(float) * BLC, hipMemcpyDeviceToDevice,
                   stream);

    for (int si = 0; si < 4; ++si) {
        const int k = 999 - si * 250;
        const int kp = (k - 250 > 0) ? (k - 250) : 0;
        const float t_feat = (float)k / 1000.0f;
        const float h_lam = lam_[kp] - lam_[k];
        const float base_a = alpha_[kp] / alpha_[k];
        const float base_b = sigma_[kp] * (expf(h_lam) - 1.0f);

        hipMemsetAsync(accum, 0, 2 * sizeof(float), stream);
        gemm_kernel<1><<<dim3(8, 256), 256, 0, stream>>>(
            z, W1, b1, tw, t_feat, h, M_DIM, H_DIM, C_DIM);
        gemm_kernel<0><<<dim3(2, 256), 256, 0, stream>>>(
            h, W2, b2, nullptr, 0.f, eps, M_DIM, C_DIM, H_DIM);
        entvar_kernel<<<512, 256, 0, stream>>>(eps, z, y_obs, mask, ent, accum);
        pool_kernel<<<168, 256, 0, stream>>>(ent, p1, p2, p3);
        select_kernel<<<4, 1024, 0, stream>>>(ent, p1, p2, p3, thr);
        update_kernel<<<8192, 256, 0, stream>>>(z, y_obs, mask, eps, ent, p1,
                                                p2, p3, thr, accum, base_a,
                                                base_b, h_lam);
    }
}

// Round 2
// 640.062 us; speedup vs baseline: 5.6545x; 5.6545x over previous
//
#include <hip/hip_runtime.h>
#include <math.h>
#include <stdint.h>

#define L_DIM 1024
#define C_DIM 128
#define H_DIM 512
#define B_DIM 16
#define LC (L_DIM * C_DIM)      // 131072
#define BLC (B_DIM * LC)        // 2097152
#define M_DIM (B_DIM * L_DIM)   // 16384

// ---------------- monotone float -> uint (order-preserving) ----------------
__device__ __forceinline__ unsigned ford(float x) {
    unsigned u = __float_as_uint(x);
    return (u & 0x80000000u) ? ~u : (u | 0x80000000u);
}

// ---------------- tiled fp32 GEMM, C = fuse(A@B + bias [+ t*tw]) -----------
// A: [M,K] row-major, B: [K,N] row-major. M%64==0, N%64==0, K%16==0.
// FUSE==1: gelu(x + bias[n] + t_feat*tw[n]) (tanh approx, JAX default)
// FUSE==0: x + bias[n]
template <int FUSE>
__global__ __launch_bounds__(256) void gemm_kernel(
    const float* __restrict__ A, const float* __restrict__ B,
    const float* __restrict__ bias, const float* __restrict__ tw,
    float t_feat, float* __restrict__ C, int M, int N, int K) {
    __shared__ float As[16][68];  // [k][m], padded
    __shared__ float Bs[16][68];  // [k][n], padded
    const int tid = threadIdx.x;
    const int tx = tid & 15;
    const int ty = tid >> 4;
    const int m0 = blockIdx.y * 64;
    const int n0 = blockIdx.x * 64;

    const int la_row = tid >> 2;         // 0..63
    const int la_k = (tid & 3) << 2;     // 0,4,8,12
    const int lb_row = tid >> 4;         // 0..15
    const int lb_col = (tid & 15) << 2;  // 0..60

    float acc[4][4] = {};

    for (int k0 = 0; k0 < K; k0 += 16) {
        float4 a4 = *(const float4*)(A + (size_t)(m0 + la_row) * K + (k0 + la_k));
        float4 b4 = *(const float4*)(B + (size_t)(k0 + lb_row) * N + (n0 + lb_col));
        __syncthreads();  // previous tile's compute done before overwrite
        As[la_k + 0][la_row] = a4.x;
        As[la_k + 1][la_row] = a4.y;
        As[la_k + 2][la_row] = a4.z;
        As[la_k + 3][la_row] = a4.w;
        *(float4*)(&Bs[lb_row][lb_col]) = b4;
        __syncthreads();
#pragma unroll
        for (int kk = 0; kk < 16; ++kk) {
            float4 av = *(const float4*)(&As[kk][ty << 2]);
            float4 bv = *(const float4*)(&Bs[kk][tx << 2]);
            acc[0][0] += av.x * bv.x; acc[0][1] += av.x * bv.y;
            acc[0][2] += av.x * bv.z; acc[0][3] += av.x * bv.w;
            acc[1][0] += av.y * bv.x; acc[1][1] += av.y * bv.y;
            acc[1][2] += av.y * bv.z; acc[1][3] += av.y * bv.w;
            acc[2][0] += av.z * bv.x; acc[2][1] += av.z * bv.y;
            acc[2][2] += av.z * bv.z; acc[2][3] += av.z * bv.w;
            acc[3][0] += av.w * bv.x; acc[3][1] += av.w * bv.y;
            acc[3][2] += av.w * bv.z; acc[3][3] += av.w * bv.w;
        }
    }

#pragma unroll
    for (int i = 0; i < 4; ++i) {
        const int m = m0 + (ty << 2) + i;
        float o[4];
#pragma unroll
        for (int j = 0; j < 4; ++j) {
            const int n = n0 + (tx << 2) + j;
            float v = acc[i][j] + bias[n];
            if (FUSE) {
                v += t_feat * tw[n];
                float inner = 0.7978845608028654f * (v + 0.044715f * v * v * v);
                v = 0.5f * v * (1.0f + tanhf(inner));
            }
            o[j] = v;
        }
        *(float4*)(C + (size_t)m * N + n0 + (tx << 2)) =
            make_float4(o[0], o[1], o[2], o[3]);
    }
}

// ---------------- ent_pix + var(obs_err) stats -----------------------------
__global__ __launch_bounds__(256) void entvar_kernel(
    const float* __restrict__ eps, const float* __restrict__ z,
    const float* __restrict__ y, const float* __restrict__ mk,
    float* __restrict__ ent, float* __restrict__ accum) {
    const int p = blockIdx.x * 256 + threadIdx.x;  // pixel index < LC
    float sa = 0.f, s1 = 0.f, s2 = 0.f;
#pragma unroll
    for (int b = 0; b < B_DIM; ++b) {
        const size_t i = (size_t)b * LC + p;
        sa += fabsf(eps[i]);
        const float oe = (z[i] - y[i]) * mk[i];
        s1 += oe;
        s2 += oe * oe;
    }
    ent[p] = sa * (1.0f / 16.0f);
    // wave reduce (64 lanes)
    for (int off = 32; off; off >>= 1) {
        s1 += __shfl_down(s1, off);
        s2 += __shfl_down(s2, off);
    }
    __shared__ float r1[4], r2[4];
    const int w = threadIdx.x >> 6, lane = threadIdx.x & 63;
    if (lane == 0) { r1[w] = s1; r2[w] = s2; }
    __syncthreads();
    if (threadIdx.x == 0) {
        atomicAdd(&accum[0], r1[0] + r1[1] + r1[2] + r1[3]);
        atomicAdd(&accum[1], r2[0] + r2[1] + r2[2] + r2[3]);
    }
}

// ---------------- multiscale pooling (w = 2,4,8 from ent) ------------------
__global__ __launch_bounds__(256) void pool_kernel(
    const float* __restrict__ ent, float* __restrict__ p1,
    float* __restrict__ p2, float* __restrict__ p3) {
    const int idx = blockIdx.x * 256 + threadIdx.x;  // < 43008
    if (idx < 32768) {  // w=2: 512 x 64
        const int r = idx >> 6, c = idx & 63;
        float s = 0.f;
#pragma unroll
        for (int i = 0; i < 2; ++i)
#pragma unroll
            for (int j = 0; j < 2; ++j) s += ent[((r * 2 + i) << 7) + c * 2 + j];
        p1[idx] = s * 0.25f;
    } else if (idx < 40960) {  // w=4: 256 x 32
        const int t = idx - 32768;
        const int r = t >> 5, c = t & 31;
        float s = 0.f;
#pragma unroll
        for (int i = 0; i < 4; ++i)
#pragma unroll
            for (int j = 0; j < 4; ++j) s += ent[((r * 4 + i) << 7) + c * 4 + j];
        p2[t] = s * 0.0625f;
    } else {  // w=8: 128 x 16
        const int t = idx - 40960;
        const int r = t >> 4, c = t & 15;
        float s = 0.f;
#pragma unroll
        for (int i = 0; i < 8; ++i)
#pragma unroll
            for (int j = 0; j < 8; ++j) s += ent[((r * 8 + i) << 7) + c * 8 + j];
        p3[t] = s * (1.0f / 64.0f);
    }
}

// ---------------- multi-block radix-select: histogram pass -----------------
// Block mapping: scale0 = blocks [0,64), scale1 = [64,80), scale2 = [80,84),
// scale3 = block 84. Each block covers 2048 elements.
// Per-wave-private LDS histograms (plain LDS atomics absorb same-digit storms
// without the ballot-serialization loop), then one global atomicAdd per bin.
__global__ __launch_bounds__(256) void hist_kernel(
    const float* __restrict__ e0, const float* __restrict__ e1,
    const float* __restrict__ e2, const float* __restrict__ e3,
    unsigned* __restrict__ ghist, const unsigned* __restrict__ gprefix,
    int shift) {
    const int bid = blockIdx.x;
    const float* data;
    int scale, base;
    if (bid < 64) { scale = 0; data = e0; base = bid * 2048; }
    else if (bid < 80) { scale = 1; data = e1; base = (bid - 64) * 2048; }
    else if (bid < 84) { scale = 2; data = e2; base = (bid - 80) * 2048; }
    else { scale = 3; data = e3; base = 0; }

    __shared__ unsigned hist[4][256];
    const int w = threadIdx.x >> 6;
#pragma unroll
    for (int i = threadIdx.x; i < 1024; i += 256) ((unsigned*)hist)[i] = 0u;
    __syncthreads();

    // For shift==24 hmask==0 -> every element valid, prefix value irrelevant
    // (so the poisoned first read of gprefix is harmless).
    const unsigned prefix = gprefix[scale];
    const unsigned hmask = (shift == 24) ? 0u : (0xFFFFFFFFu << (shift + 8));

#pragma unroll
    for (int i = threadIdx.x; i < 2048; i += 256) {
        const unsigned u = ford(data[base + i]);
        if ((u & hmask) == (prefix & hmask))
            atomicAdd(&hist[w][(u >> shift) & 255u], 1u);
    }
    __syncthreads();
    const unsigned c = hist[0][threadIdx.x] + hist[1][threadIdx.x] +
                       hist[2][threadIdx.x] + hist[3][threadIdx.x];
    if (c) atomicAdd(&ghist[scale * 256 + threadIdx.x], c);
}

// ---------------- multi-block radix-select: scan pass ----------------------
// One block, 256 threads. For each scale: suffix-sum the 256-bin histogram,
// pick the digit (largest bin b with suffix_sum(b) >= k_rem), update
// prefix/krem, zero the histogram for the next pass.
__global__ __launch_bounds__(256) void scan_kernel(
    unsigned* __restrict__ ghist, unsigned* __restrict__ gprefix,
    unsigned* __restrict__ gkrem, int shift) {
    __shared__ unsigned sh[256];
    const unsigned Kс[4] = {26214u, 6553u, 1638u, 409u};
    const int t = threadIdx.x;
#pragma unroll
    for (int s = 0; s < 4; ++s) {
        sh[t] = ghist[s * 256 + t];
        __syncthreads();
#pragma unroll
        for (int off = 1; off < 256; off <<= 1) {
            const unsigned v = (t + off < 256) ? sh[t + off] : 0u;
            __syncthreads();
            sh[t] += v;
            __syncthreads();
        }
        const unsigned suf = sh[t];
        const unsigned sufn = (t < 255) ? sh[t + 1] : 0u;
        const unsigned krem = (shift == 24) ? Kс[s] : gkrem[s];
        const unsigned pref = (shift == 24) ? 0u : gprefix[s];
        if (suf >= krem && sufn < krem) {  // unique: suf is non-increasing
            gprefix[s] = pref | ((unsigned)t << shift);
            gkrem[s] = krem - sufn;
        }
        ghist[s * 256 + t] = 0u;  // ready for next pass
        __syncthreads();
    }
}

// ---------------- fused update: guidance + scale-select + DPM step ---------
__global__ __launch_bounds__(256) void update_kernel(
    float* __restrict__ z, const float* __restrict__ y,
    const float* __restrict__ mk, const float* __restrict__ eps,
    const float* __restrict__ ent, const float* __restrict__ p1,
    const float* __restrict__ p2, const float* __restrict__ p3,
    const unsigned* __restrict__ thr, const float* __restrict__ accum,
    float base_a, float base_b, float h_lam) {
    const int idx = blockIdx.x * 256 + threadIdx.x;  // < BLC
    const int p = idx & (LC - 1);
    const int l = p >> 7;
    const int c = p & 127;

    const float mean = accum[0] * (1.0f / (float)BLC);
    const float var = accum[1] * (1.0f / (float)BLC) - mean * mean;

    const float zi = z[idx];
    const float oe = (zi - y[idx]) * mk[idx];
    const float guid = -oe / (var + 1e-8f);
    const float ei = eps[idx];

    // finest selected scale wins (coarse->fine overwrite in reference)
    float ent_v = 0.f;
    bool sel = false;
    {
        const float v0 = ent[p];
        if (ford(v0) >= thr[0]) { ent_v = v0; sel = true; }
        else {
            const float v1 = p1[((l >> 1) << 6) + (c >> 1)];
            if (ford(v1) >= thr[1]) { ent_v = v1; sel = true; }
            else {
                const float v2 = p2[((l >> 2) << 5) + (c >> 2)];
                if (ford(v2) >= thr[2]) { ent_v = v2; sel = true; }
                else {
                    const float v3 = p3[((l >> 3) << 4) + (c >> 3)];
                    if (ford(v3) >= thr[3]) { ent_v = v3; sel = true; }
                }
            }
        }
    }
    if (sel) {
        // order = 1 + (ent>0.1) + (ent>0.5); corr per Taylor expansion
        float corr;
        if (ent_v > 0.5f)
            corr = 1.0f + h_lam + h_lam * h_lam * (1.0f / 3.0f);
        else if (ent_v > 0.1f)
            corr = 1.0f + 0.5f * h_lam;
        else
            corr = 1.0f;
        const float gs = 2.0f * ent_v / (ent_v + 1.0f);
        z[idx] = base_a * zi - base_b * (corr * ei) + gs * guid;
    }
}

// ---------------------------------------------------------------------------
extern "C" void kernel_launch(void* const* d_in, const int* in_sizes, int n_in,
                              void* d_out, int out_size, void* d_ws,
                              size_t ws_size, hipStream_t stream) {
    const float* y_obs = (const float*)d_in[0];
    const float* mask = (const float*)d_in[1];
    const float* z_init = (const float*)d_in[2];
    const float* W1 = (const float*)d_in[3];
    const float* b1 = (const float*)d_in[4];
    const float* W2 = (const float*)d_in[5];
    const float* b2 = (const float*)d_in[6];
    const float* tw = (const float*)d_in[7];
    float* z = (float*)d_out;
    float* ws = (float*)d_ws;

    // workspace layout (floats)
    float* h = ws;                       // 16384*512 = 8388608
    float* eps = ws + 8388608;           // 2097152
    float* ent = ws + 10485760;          // 131072
    float* p1 = ws + 10616832;           // 32768
    float* p2 = ws + 10649600;           // 8192
    float* p3 = ws + 10657792;           // 2048
    unsigned* ghist = (unsigned*)(ws + 10659840);   // 4*256
    unsigned* gprefix = (unsigned*)(ws + 10660864); // 4
    unsigned* gkrem = (unsigned*)(ws + 10660868);   // 4
    float* accum = ws + 10660872;                   // 2

    // diffusion schedule in fp32 (matches jnp fp32 cumprod semantics);
    // input-independent -> safe to bake into captured kernel args
    float alpha_[1000], sigma_[1000], lam_[1000];
    {
        float ac = 1.0f;
        for (int i = 0; i < 1000; ++i) {
            const float beta =
                1e-4f + (0.02f - 1e-4f) * ((float)i / 999.0f);
            ac = ac * (1.0f - beta);
            alpha_[i] = sqrtf(ac);
            sigma_[i] = sqrtf(1.0f - ac);
            lam_[i] = logf(alpha_[i]) - logf(sigma_[i]);
        }
    }

    hipMemcpyAsync(z, z_init, sizeof(float) * BLC, hipMemcpyDeviceToDevice,
                   stream);
    // ghist must start zeroed (ws is poisoned 0xAA); scan_kernel re-zeroes it
    // after every pass, so once per call suffices.
    hipMemsetAsync(ghist, 0, 4 * 256 * sizeof(unsigned), stream);

    for (int si = 0; si < 4; ++si) {
        const int k = 999 - si * 250;
        const int kp = (k - 250 > 0) ? (k - 250) : 0;
        const float t_feat = (float)k / 1000.0f;
        const float h_lam = lam_[kp] - lam_[k];
        const float base_a = alpha_[kp] / alpha_[k];
        const float base_b = sigma_[kp] * (expf(h_lam) - 1.0f);

        hipMemsetAsync(accum, 0, 2 * sizeof(float), stream);
        gemm_kernel<1><<<dim3(8, 256), 256, 0, stream>>>(
            z, W1, b1, tw, t_feat, h, M_DIM, H_DIM, C_DIM);
        gemm_kernel<0><<<dim3(2, 256), 256, 0, stream>>>(
            h, W2, b2, nullptr, 0.f, eps, M_DIM, C_DIM, H_DIM);
        entvar_kernel<<<512, 256, 0, stream>>>(eps, z, y_obs, mask, ent, accum);
        pool_kernel<<<168, 256, 0, stream>>>(ent, p1, p2, p3);
        for (int shift = 24; shift >= 0; shift -= 8) {
            hist_kernel<<<85, 256, 0, stream>>>(ent, p1, p2, p3, ghist,
                                                gprefix, shift);
            scan_kernel<<<1, 256, 0, stream>>>(ghist, gprefix, gkrem, shift);
        }
        update_kernel<<<8192, 256, 0, stream>>>(z, y_obs, mask, eps, ent, p1,
                                                p2, p3, gprefix, accum, base_a,
                                                base_b, h_lam);
    }
}

// Round 5
// 499.605 us; speedup vs baseline: 7.2441x; 1.2811x over previous
//
#include <hip/hip_runtime.h>
#include <math.h>
#include <stdint.h>

#define L_DIM 1024
#define C_DIM 128
#define H_DIM 512
#define B_DIM 16
#define LC (L_DIM * C_DIM)      // 131072
#define BLC (B_DIM * LC)        // 2097152
#define M_DIM (B_DIM * L_DIM)   // 16384

typedef __attribute__((ext_vector_type(8))) short short8;
typedef __attribute__((ext_vector_type(4))) float floatx4;

// ---------------- monotone float -> uint (order-preserving) ----------------
__device__ __forceinline__ unsigned ford(float x) {
    unsigned u = __float_as_uint(x);
    return (u & 0x80000000u) ? ~u : (u | 0x80000000u);
}

// ---------------- truncation 3-way bf16 split: x = h + m + l + O(2^-24 x) --
// All subtractions are exact (Sterbenz); components h~2^0, m~2^-8, l~2^-16.
__device__ __forceinline__ void split3(float x, unsigned& uh, unsigned& um,
                                       unsigned& ul) {
    uh = __float_as_uint(x);
    const float r1 = x - __uint_as_float(uh & 0xffff0000u);
    um = __float_as_uint(r1);
    const float r2 = r1 - __uint_as_float(um & 0xffff0000u);
    ul = __float_as_uint(r2);
}

// ---------------- W pre-split into MFMA B-frag layout (h/m/l bf16) ---------
// W1 [128,512]: frag idx = ((kt*32+nt)*64+lane)*8+j ; k=kt*32+quad*8+j, n=nt*16+(lane&15)
// W2 [512,128]: frag idx = ((kt*8+nt)*64+lane)*8+j  ; same k/n formulas
__global__ __launch_bounds__(256) void wsplit_kernel(
    const float* __restrict__ W1, const float* __restrict__ W2,
    unsigned short* __restrict__ W1h, unsigned short* __restrict__ W1m,
    unsigned short* __restrict__ W1l, unsigned short* __restrict__ W2h,
    unsigned short* __restrict__ W2m, unsigned short* __restrict__ W2l) {
    const int t = blockIdx.x * 256 + threadIdx.x;  // < 131072
    unsigned uh, um, ul;
    if (t < 65536) {
        const int j = t & 7, lane = (t >> 3) & 63, nt = (t >> 9) & 31,
                  kt = (t >> 14) & 3;
        const int k = kt * 32 + (lane >> 4) * 8 + j;
        const int n = nt * 16 + (lane & 15);
        split3(W1[k * 512 + n], uh, um, ul);
        W1h[t] = (unsigned short)(uh >> 16);
        W1m[t] = (unsigned short)(um >> 16);
        W1l[t] = (unsigned short)(ul >> 16);
    } else {
        const int t2 = t - 65536;
        const int j = t2 & 7, lane = (t2 >> 3) & 63, nt = (t2 >> 9) & 7,
                  kt = (t2 >> 12) & 15;
        const int k = kt * 32 + (lane >> 4) * 8 + j;
        const int n = nt * 16 + (lane & 15);
        split3(W2[k * 128 + n], uh, um, ul);
        W2h[t2] = (unsigned short)(uh >> 16);
        W2m[t2] = (unsigned short)(um >> 16);
        W2l[t2] = (unsigned short)(ul >> 16);
    }
}

// 6-term bf16x3 MFMA accumulate (small terms first)
#define MFMA6(AH, AM, AL, BH, BM, BL, ACC)                                    \
    ACC = __builtin_amdgcn_mfma_f32_16x16x32_bf16(AL, BH, ACC, 0, 0, 0);      \
    ACC = __builtin_amdgcn_mfma_f32_16x16x32_bf16(AM, BM, ACC, 0, 0, 0);      \
    ACC = __builtin_amdgcn_mfma_f32_16x16x32_bf16(AH, BL, ACC, 0, 0, 0);      \
    ACC = __builtin_amdgcn_mfma_f32_16x16x32_bf16(AM, BH, ACC, 0, 0, 0);      \
    ACC = __builtin_amdgcn_mfma_f32_16x16x32_bf16(AH, BM, ACC, 0, 0, 0);      \
    ACC = __builtin_amdgcn_mfma_f32_16x16x32_bf16(AH, BH, ACC, 0, 0, 0);

// ---------------- fused MLP: eps = (gelu(z@W1 + b1 + t*tw))@W2 + b2 --------
// Also ent[l][c] = mean_b |eps| and s1/s2 of obs_err (atomics into accum).
// Block: 512 thr (8 waves), owns 64 rows = 16 b x 4 l (row t = il*16 + b).
// bf16x3 split GEMMs (6 MFMAs) -> fp32-class accuracy (bf16x2 in R3/R4
// caused top-k boundary flips -> absmax 18000).
__global__ __launch_bounds__(512, 2) void mlp_kernel(
    const float* __restrict__ z, const float* __restrict__ y,
    const float* __restrict__ mk,
    const unsigned short* __restrict__ W1h, const unsigned short* __restrict__ W1m,
    const unsigned short* __restrict__ W1l, const unsigned short* __restrict__ W2h,
    const unsigned short* __restrict__ W2m, const unsigned short* __restrict__ W2l,
    const float* __restrict__ b1, const float* __restrict__ tw,
    const float* __restrict__ b2, float t_feat,
    float* __restrict__ eps_out, float* __restrict__ ent,
    float* __restrict__ accum) {
    __shared__ unsigned lds_hm[64 * 132];        // h|m packed, stride 132
    __shared__ unsigned short lds_l[64 * 136];   // l, stride 136
    __shared__ float red1[8], red2[8];
    const int tid = threadIdx.x;
    const int w = tid >> 6, lane = tid & 63;
    const int quad = lane >> 4, m16 = lane & 15;
    const int l0 = blockIdx.x * 4;

    // ================= GEMM1 (full): h pre-act tiles for all 4 quarters ====
    floatx4 acc1[16];  // [q*4 + il]; wave's nt = q*8+w
#pragma unroll
    for (int i = 0; i < 16; ++i) acc1[i] = (floatx4){0.f, 0.f, 0.f, 0.f};

#pragma unroll
    for (int kt = 0; kt < 4; ++kt) {
        short8 Ah[4], Am[4], Al[4];
#pragma unroll
        for (int il = 0; il < 4; ++il) {
            const float* zp = z + ((size_t)m16 * 1024 + l0 + il) * 128 +
                              kt * 32 + quad * 8;
            const float4 u0 = *(const float4*)zp;
            const float4 u1 = *(const float4*)(zp + 4);
            const float xs[8] = {u0.x, u0.y, u0.z, u0.w,
                                 u1.x, u1.y, u1.z, u1.w};
            unsigned uh[8], um[8], ul[8];
#pragma unroll
            for (int jj = 0; jj < 8; ++jj) split3(xs[jj], uh[jj], um[jj], ul[jj]);
            union { short8 v; unsigned u[4]; } ah, am, al;
#pragma unroll
            for (int p = 0; p < 4; ++p) {
                ah.u[p] = (uh[2 * p] >> 16) | (uh[2 * p + 1] & 0xffff0000u);
                am.u[p] = (um[2 * p] >> 16) | (um[2 * p + 1] & 0xffff0000u);
                al.u[p] = (ul[2 * p] >> 16) | (ul[2 * p + 1] & 0xffff0000u);
            }
            Ah[il] = ah.v; Am[il] = am.v; Al[il] = al.v;
        }
#pragma unroll
        for (int q = 0; q < 4; ++q) {
            const int nt1 = q * 8 + w;
            const size_t off = ((size_t)(kt * 32 + nt1) * 64 + lane) * 8;
            const short8 bh = *(const short8*)(W1h + off);
            const short8 bm = *(const short8*)(W1m + off);
            const short8 bl = *(const short8*)(W1l + off);
#pragma unroll
            for (int il = 0; il < 4; ++il) {
                floatx4 a = acc1[q * 4 + il];
                MFMA6(Ah[il], Am[il], Al[il], bh, bm, bl, a);
                acc1[q * 4 + il] = a;
            }
        }
    }

    // ================= quarter phases: h -> LDS, GEMM2 partial-K ===========
    floatx4 acc2[4];  // [ii*2 + jj]: il = ila+ii, nt = ntg*2+jj
#pragma unroll
    for (int i = 0; i < 4; ++i) acc2[i] = (floatx4){0.f, 0.f, 0.f, 0.f};
    const int ila = (w & 1) * 2;
    const int ntg = w >> 1;  // 0..3

    for (int q = 0; q < 4; ++q) {
        if (q) __syncthreads();  // previous quarter's reads done
        // gelu + split + pack this wave's quarter columns into LDS
        {
            const int coll = w * 16 + m16;       // quarter-local col 0..127
            const int colg = q * 128 + coll;     // global H col
            const float bb = b1[colg] + t_feat * tw[colg];
#pragma unroll
            for (int il = 0; il < 4; ++il) {
#pragma unroll
                for (int r = 0; r < 4; ++r) {
                    float x = acc1[q * 4 + il][r] + bb;
                    const float inner =
                        0.7978845608028654f * (x + 0.044715f * x * x * x);
                    x = 0.5f * x * (1.0f + tanhf(inner));
                    unsigned uh, um, ul;
                    split3(x, uh, um, ul);
                    const int row = il * 16 + quad * 4 + r;
                    lds_hm[row * 132 + coll] =
                        (uh >> 16) | (um & 0xffff0000u);
                    lds_l[row * 136 + coll] = (unsigned short)(ul >> 16);
                }
            }
        }
        __syncthreads();

        // GEMM2: acc2 += h[:, quarter] @ W2[quarter, :]
#pragma unroll
        for (int ktl = 0; ktl < 4; ++ktl) {
            short8 Ah2[2], Am2[2], Al2[2];
#pragma unroll
            for (int ii = 0; ii < 2; ++ii) {
                const int row = (ila + ii) * 16 + m16;
                const unsigned* p = &lds_hm[row * 132 + ktl * 32 + quad * 8];
                const uint4 a = *(const uint4*)p;
                const uint4 b = *(const uint4*)(p + 4);
                union { short8 v; unsigned u[4]; } ah, am;
                ah.u[0] = (a.x & 0xffffu) | (a.y << 16);
                ah.u[1] = (a.z & 0xffffu) | (a.w << 16);
                ah.u[2] = (b.x & 0xffffu) | (b.y << 16);
                ah.u[3] = (b.z & 0xffffu) | (b.w << 16);
                am.u[0] = (a.x >> 16) | (a.y & 0xffff0000u);
                am.u[1] = (a.z >> 16) | (a.w & 0xffff0000u);
                am.u[2] = (b.x >> 16) | (b.y & 0xffff0000u);
                am.u[3] = (b.z >> 16) | (b.w & 0xffff0000u);
                Ah2[ii] = ah.v;
                Am2[ii] = am.v;
                Al2[ii] = *(const short8*)(&lds_l[row * 136 + ktl * 32 +
                                                  quad * 8]);
            }
            const int ktg = q * 4 + ktl;
#pragma unroll
            for (int jj = 0; jj < 2; ++jj) {
                const int nt = ntg * 2 + jj;
                const size_t off = ((size_t)(ktg * 8 + nt) * 64 + lane) * 8;
                const short8 bh = *(const short8*)(W2h + off);
                const short8 bm = *(const short8*)(W2m + off);
                const short8 bl = *(const short8*)(W2l + off);
#pragma unroll
                for (int ii = 0; ii < 2; ++ii) {
                    floatx4 a = acc2[ii * 2 + jj];
                    MFMA6(Ah2[ii], Am2[ii], Al2[ii], bh, bm, bl, a);
                    acc2[ii * 2 + jj] = a;
                }
            }
        }
    }

    // epilogue: +b2, write eps, reduce ent = mean_b |eps|
#pragma unroll
    for (int ii = 0; ii < 2; ++ii) {
        const int il = ila + ii;
#pragma unroll
        for (int jj = 0; jj < 2; ++jj) {
            const int nt = ntg * 2 + jj;
            const int col = nt * 16 + m16;
            const float bb2 = b2[col];
            float pa = 0.f;
#pragma unroll
            for (int r = 0; r < 4; ++r) {
                const float e = acc2[ii * 2 + jj][r] + bb2;
                const int b = quad * 4 + r;
                eps_out[((size_t)b * 1024 + l0 + il) * 128 + col] = e;
                pa += fabsf(e);
            }
            pa += __shfl_xor(pa, 16);
            pa += __shfl_xor(pa, 32);
            if (quad == 0)
                ent[(l0 + il) * 128 + col] = pa * (1.0f / 16.0f);
        }
    }

    // obs_err stats over this block's 64 rows
    float s1 = 0.f, s2 = 0.f;
#pragma unroll
    for (int e = 0; e < 4; ++e) {
        const int f = tid * 16 + e * 4;  // < 8192, stays within one row
        const int lr = f >> 7, c = f & 127;
        const int b = lr & 15, il = lr >> 4;
        const size_t g = ((size_t)b * 1024 + l0 + il) * 128 + c;
        const float4 zv = *(const float4*)(z + g);
        const float4 yv = *(const float4*)(y + g);
        const float4 mv = *(const float4*)(mk + g);
        float oe;
        oe = (zv.x - yv.x) * mv.x; s1 += oe; s2 += oe * oe;
        oe = (zv.y - yv.y) * mv.y; s1 += oe; s2 += oe * oe;
        oe = (zv.z - yv.z) * mv.z; s1 += oe; s2 += oe * oe;
        oe = (zv.w - yv.w) * mv.w; s1 += oe; s2 += oe * oe;
    }
#pragma unroll
    for (int off = 32; off; off >>= 1) {
        s1 += __shfl_down(s1, off);
        s2 += __shfl_down(s2, off);
    }
    if (lane == 0) { red1[w] = s1; red2[w] = s2; }
    __syncthreads();
    if (tid == 0) {
        float a1 = 0.f, a2 = 0.f;
#pragma unroll
        for (int i = 0; i < 8; ++i) { a1 += red1[i]; a2 += red2[i]; }
        atomicAdd(&accum[0], a1);
        atomicAdd(&accum[1], a2);
    }
}

// ---------------- multiscale pooling (w = 2,4,8 from ent) ------------------
__global__ __launch_bounds__(256) void pool_kernel(
    const float* __restrict__ ent, float* __restrict__ p1,
    float* __restrict__ p2, float* __restrict__ p3) {
    const int idx = blockIdx.x * 256 + threadIdx.x;  // < 43008
    if (idx < 32768) {  // w=2: 512 x 64
        const int r = idx >> 6, c = idx & 63;
        float s = 0.f;
#pragma unroll
        for (int i = 0; i < 2; ++i)
#pragma unroll
            for (int j = 0; j < 2; ++j) s += ent[((r * 2 + i) << 7) + c * 2 + j];
        p1[idx] = s * 0.25f;
    } else if (idx < 40960) {  // w=4: 256 x 32
        const int t = idx - 32768;
        const int r = t >> 5, c = t & 31;
        float s = 0.f;
#pragma unroll
        for (int i = 0; i < 4; ++i)
#pragma unroll
            for (int j = 0; j < 4; ++j) s += ent[((r * 4 + i) << 7) + c * 4 + j];
        p2[t] = s * 0.0625f;
    } else {  // w=8: 128 x 16
        const int t = idx - 40960;
        const int r = t >> 4, c = t & 15;
        float s = 0.f;
#pragma unroll
        for (int i = 0; i < 8; ++i)
#pragma unroll
            for (int j = 0; j < 8; ++j) s += ent[((r * 8 + i) << 7) + c * 8 + j];
        p3[t] = s * (1.0f / 64.0f);
    }
}

// ---------------- multi-block radix-select: histogram pass -----------------
__global__ __launch_bounds__(256) void hist_kernel(
    const float* __restrict__ e0, const float* __restrict__ e1,
    const float* __restrict__ e2, const float* __restrict__ e3,
    unsigned* __restrict__ ghist, const unsigned* __restrict__ gprefix,
    int shift) {
    const int bid = blockIdx.x;
    const float* data;
    int scale, base;
    if (bid < 64) { scale = 0; data = e0; base = bid * 2048; }
    else if (bid < 80) { scale = 1; data = e1; base = (bid - 64) * 2048; }
    else if (bid < 84) { scale = 2; data = e2; base = (bid - 80) * 2048; }
    else { scale = 3; data = e3; base = 0; }

    __shared__ unsigned hist[4][256];
    const int w = threadIdx.x >> 6;
#pragma unroll
    for (int i = threadIdx.x; i < 1024; i += 256) ((unsigned*)hist)[i] = 0u;
    __syncthreads();

    const unsigned prefix = gprefix[scale];
    const unsigned hmask = (shift == 24) ? 0u : (0xFFFFFFFFu << (shift + 8));

#pragma unroll
    for (int i = threadIdx.x; i < 2048; i += 256) {
        const unsigned u = ford(data[base + i]);
        if ((u & hmask) == (prefix & hmask))
            atomicAdd(&hist[w][(u >> shift) & 255u], 1u);
    }
    __syncthreads();
    const unsigned c = hist[0][threadIdx.x] + hist[1][threadIdx.x] +
                       hist[2][threadIdx.x] + hist[3][threadIdx.x];
    if (c) atomicAdd(&ghist[scale * 256 + threadIdx.x], c);
}

// ---------------- multi-block radix-select: scan pass ----------------------
__global__ __launch_bounds__(256) void scan_kernel(
    unsigned* __restrict__ ghist, unsigned* __restrict__ gprefix,
    unsigned* __restrict__ gkrem, int shift) {
    __shared__ unsigned sh[256];
    const unsigned Kc[4] = {26214u, 6553u, 1638u, 409u};
    const int t = threadIdx.x;
#pragma unroll
    for (int s = 0; s < 4; ++s) {
        sh[t] = ghist[s * 256 + t];
        __syncthreads();
#pragma unroll
        for (int off = 1; off < 256; off <<= 1) {
            const unsigned v = (t + off < 256) ? sh[t + off] : 0u;
            __syncthreads();
            sh[t] += v;
            __syncthreads();
        }
        const unsigned suf = sh[t];
        const unsigned sufn = (t < 255) ? sh[t + 1] : 0u;
        const unsigned krem = (shift == 24) ? Kc[s] : gkrem[s];
        const unsigned pref = (shift == 24) ? 0u : gprefix[s];
        if (suf >= krem && sufn < krem) {  // unique: suf non-increasing
            gprefix[s] = pref | ((unsigned)t << shift);
            gkrem[s] = krem - sufn;
        }
        ghist[s * 256 + t] = 0u;  // ready for next pass
        __syncthreads();
    }
}

// ---------------- fused update: guidance + scale-select + DPM step ---------
__global__ __launch_bounds__(256) void update_kernel(
    float* __restrict__ z, const float* __restrict__ y,
    const float* __restrict__ mk, const float* __restrict__ eps,
    const float* __restrict__ ent, const float* __restrict__ p1,
    const float* __restrict__ p2, const float* __restrict__ p3,
    const unsigned* __restrict__ thr, const float* __restrict__ accum,
    float base_a, float base_b, float h_lam) {
    const int idx = blockIdx.x * 256 + threadIdx.x;  // < BLC
    const int p = idx & (LC - 1);
    const int l = p >> 7;
    const int c = p & 127;

    const float mean = accum[0] * (1.0f / (float)BLC);
    const float var = accum[1] * (1.0f / (float)BLC) - mean * mean;

    const float zi = z[idx];
    const float oe = (zi - y[idx]) * mk[idx];
    const float guid = -oe / (var + 1e-8f);
    const float ei = eps[idx];

    float ent_v = 0.f;
    bool sel = false;
    {
        const float v0 = ent[p];
        if (ford(v0) >= thr[0]) { ent_v = v0; sel = true; }
        else {
            const float v1 = p1[((l >> 1) << 6) + (c >> 1)];
            if (ford(v1) >= thr[1]) { ent_v = v1; sel = true; }
            else {
                const float v2 = p2[((l >> 2) << 5) + (c >> 2)];
                if (ford(v2) >= thr[2]) { ent_v = v2; sel = true; }
                else {
                    const float v3 = p3[((l >> 3) << 4) + (c >> 3)];
                    if (ford(v3) >= thr[3]) { ent_v = v3; sel = true; }
                }
            }
        }
    }
    if (sel) {
        float corr;
        if (ent_v > 0.5f)
            corr = 1.0f + h_lam + h_lam * h_lam * (1.0f / 3.0f);
        else if (ent_v > 0.1f)
            corr = 1.0f + 0.5f * h_lam;
        else
            corr = 1.0f;
        const float gs = 2.0f * ent_v / (ent_v + 1.0f);
        z[idx] = base_a * zi - base_b * (corr * ei) + gs * guid;
    }
}

// ---------------------------------------------------------------------------
extern "C" void kernel_launch(void* const* d_in, const int* in_sizes, int n_in,
                              void* d_out, int out_size, void* d_ws,
                              size_t ws_size, hipStream_t stream) {
    const float* y_obs = (const float*)d_in[0];
    const float* mask = (const float*)d_in[1];
    const float* z_init = (const float*)d_in[2];
    const float* W1 = (const float*)d_in[3];
    const float* b1 = (const float*)d_in[4];
    const float* W2 = (const float*)d_in[5];
    const float* b2 = (const float*)d_in[6];
    const float* tw = (const float*)d_in[7];
    float* z = (float*)d_out;
    float* ws = (float*)d_ws;

    // workspace layout (float offsets)
    float* eps = ws;                                 // 2097152
    float* ent = ws + 2097152;                       // 131072
    float* p1 = ws + 2228224;                        // 32768
    float* p2 = ws + 2260992;                        // 8192
    float* p3 = ws + 2269184;                        // 2048
    unsigned* ghist = (unsigned*)(ws + 2271232);     // 1024
    unsigned* gprefix = (unsigned*)(ws + 2272256);   // 4
    unsigned* gkrem = (unsigned*)(ws + 2272260);     // 4
    float* accum = ws + 2272264;                     // 2
    unsigned short* W1h = (unsigned short*)(ws + 2272272);  // 65536 u16 each
    unsigned short* W1m = (unsigned short*)(ws + 2305040);
    unsigned short* W1l = (unsigned short*)(ws + 2337808);
    unsigned short* W2h = (unsigned short*)(ws + 2370576);
    unsigned short* W2m = (unsigned short*)(ws + 2403344);
    unsigned short* W2l = (unsigned short*)(ws + 2436112);

    // diffusion schedule in fp32 (input-independent)
    float alpha_[1000], sigma_[1000], lam_[1000];
    {
        float ac = 1.0f;
        for (int i = 0; i < 1000; ++i) {
            const float beta = 1e-4f + (0.02f - 1e-4f) * ((float)i / 999.0f);
            ac = ac * (1.0f - beta);
            alpha_[i] = sqrtf(ac);
            sigma_[i] = sqrtf(1.0f - ac);
            lam_[i] = logf(alpha_[i]) - logf(sigma_[i]);
        }
    }

    hipMemcpyAsync(z, z_init, sizeof(float) * BLC, hipMemcpyDeviceToDevice,
                   stream);
    hipMemsetAsync(ghist, 0, 4 * 256 * sizeof(unsigned), stream);
    wsplit_kernel<<<512, 256, 0, stream>>>(W1, W2, W1h, W1m, W1l, W2h, W2m,
                                           W2l);

    for (int si = 0; si < 4; ++si) {
        const int k = 999 - si * 250;
        const int kp = (k - 250 > 0) ? (k - 250) : 0;
        const float t_feat = (float)k / 1000.0f;
        const float h_lam = lam_[kp] - lam_[k];
        const float base_a = alpha_[kp] / alpha_[k];
        const float base_b = sigma_[kp] * (expf(h_lam) - 1.0f);

        hipMemsetAsync(accum, 0, 2 * sizeof(float), stream);
        mlp_kernel<<<256, 512, 0, stream>>>(
            z, y_obs, mask, W1h, W1m, W1l, W2h, W2m, W2l, b1, tw, b2, t_feat,
            eps, ent, accum);
        pool_kernel<<<168, 256, 0, stream>>>(ent, p1, p2, p3);
        for (int shift = 24; shift >= 0; shift -= 8) {
            hist_kernel<<<85, 256, 0, stream>>>(ent, p1, p2, p3, ghist,
                                                gprefix, shift);
            scan_kernel<<<1, 256, 0, stream>>>(ghist, gprefix, gkrem, shift);
        }
        update_kernel<<<8192, 256, 0, stream>>>(z, y_obs, mask, eps, ent, p1,
                                                p2, p3, gprefix, accum, base_a,
                                                base_b, h_lam);
    }
}

// Round 6
// 457.353 us; speedup vs baseline: 7.9134x; 1.0924x over previous
//
#include <hip/hip_runtime.h>
#include <math.h>
#include <stdint.h>

#define L_DIM 1024
#define C_DIM 128
#define H_DIM 512
#define B_DIM 16
#define LC (L_DIM * C_DIM)      // 131072
#define BLC (B_DIM * LC)        // 2097152
#define M_DIM (B_DIM * L_DIM)   // 16384

typedef __attribute__((ext_vector_type(8))) short short8;
typedef __attribute__((ext_vector_type(4))) float floatx4;

// ---------------- monotone float -> uint (order-preserving) ----------------
__device__ __forceinline__ unsigned ford(float x) {
    unsigned u = __float_as_uint(x);
    return (u & 0x80000000u) ? ~u : (u | 0x80000000u);
}

// ---------------- truncation 3-way bf16 split: x = h + m + l + O(2^-24 x) --
__device__ __forceinline__ void split3(float x, unsigned& uh, unsigned& um,
                                       unsigned& ul) {
    uh = __float_as_uint(x);
    const float r1 = x - __uint_as_float(uh & 0xffff0000u);
    um = __float_as_uint(r1);
    const float r2 = r1 - __uint_as_float(um & 0xffff0000u);
    ul = __float_as_uint(r2);
}

__device__ __forceinline__ float gelu_fast(float x) {
    // 0.5x(1+tanh(g)), tanh via hw exp (R2-proven numerics)
    const float g = 0.7978845608028654f * (x + 0.044715f * x * x * x);
    const float e = __expf(2.0f * g);
    const float t = 1.0f - 2.0f / (e + 1.0f);
    return 0.5f * x * (1.0f + t);
}

// ---------------- W pre-split into MFMA B-frag layout (h/m/l bf16) ---------
// W1 [128,512]: frag idx = ((kt*32+nt)*64+lane)*8+j ; k=kt*32+quad*8+j, n=nt*16+(lane&15)
// W2 [512,128]: frag idx = ((kt*8+nt)*64+lane)*8+j  ; same k/n formulas
__global__ __launch_bounds__(256) void wsplit_kernel(
    const float* __restrict__ W1, const float* __restrict__ W2,
    unsigned short* __restrict__ W1h, unsigned short* __restrict__ W1m,
    unsigned short* __restrict__ W1l, unsigned short* __restrict__ W2h,
    unsigned short* __restrict__ W2m, unsigned short* __restrict__ W2l) {
    const int t = blockIdx.x * 256 + threadIdx.x;  // < 131072
    unsigned uh, um, ul;
    if (t < 65536) {
        const int j = t & 7, lane = (t >> 3) & 63, nt = (t >> 9) & 31,
                  kt = (t >> 14) & 3;
        const int k = kt * 32 + (lane >> 4) * 8 + j;
        const int n = nt * 16 + (lane & 15);
        split3(W1[k * 512 + n], uh, um, ul);
        W1h[t] = (unsigned short)(uh >> 16);
        W1m[t] = (unsigned short)(um >> 16);
        W1l[t] = (unsigned short)(ul >> 16);
    } else {
        const int t2 = t - 65536;
        const int j = t2 & 7, lane = (t2 >> 3) & 63, nt = (t2 >> 9) & 7,
                  kt = (t2 >> 12) & 15;
        const int k = kt * 32 + (lane >> 4) * 8 + j;
        const int n = nt * 16 + (lane & 15);
        split3(W2[k * 128 + n], uh, um, ul);
        W2h[t2] = (unsigned short)(uh >> 16);
        W2m[t2] = (unsigned short)(um >> 16);
        W2l[t2] = (unsigned short)(ul >> 16);
    }
}

// 6-term bf16x3 MFMA accumulate (small terms first); error ~2^-24
#define MFMA6(AH, AM, AL, BH, BM, BL, ACC)                                    \
    ACC = __builtin_amdgcn_mfma_f32_16x16x32_bf16(AL, BH, ACC, 0, 0, 0);      \
    ACC = __builtin_amdgcn_mfma_f32_16x16x32_bf16(AM, BM, ACC, 0, 0, 0);      \
    ACC = __builtin_amdgcn_mfma_f32_16x16x32_bf16(AH, BL, ACC, 0, 0, 0);      \
    ACC = __builtin_amdgcn_mfma_f32_16x16x32_bf16(AM, BH, ACC, 0, 0, 0);      \
    ACC = __builtin_amdgcn_mfma_f32_16x16x32_bf16(AH, BM, ACC, 0, 0, 0);      \
    ACC = __builtin_amdgcn_mfma_f32_16x16x32_bf16(AH, BH, ACC, 0, 0, 0);

// read a split A-fragment (row, k-base) from packed LDS
__device__ __forceinline__ void ldsA(const unsigned* hm,
                                     const unsigned short* lr, int row,
                                     int kbase, short8& Ah, short8& Am,
                                     short8& Al) {
    const unsigned* p = &hm[row * 132 + kbase];
    const uint4 a = *(const uint4*)p;
    const uint4 b = *(const uint4*)(p + 4);
    union { short8 v; unsigned u[4]; } ah, am;
    ah.u[0] = (a.x & 0xffffu) | (a.y << 16);
    ah.u[1] = (a.z & 0xffffu) | (a.w << 16);
    ah.u[2] = (b.x & 0xffffu) | (b.y << 16);
    ah.u[3] = (b.z & 0xffffu) | (b.w << 16);
    am.u[0] = (a.x >> 16) | (a.y & 0xffff0000u);
    am.u[1] = (a.z >> 16) | (a.w & 0xffff0000u);
    am.u[2] = (b.x >> 16) | (b.y & 0xffff0000u);
    am.u[3] = (b.z >> 16) | (b.w & 0xffff0000u);
    Ah = ah.v;
    Am = am.v;
    Al = *(const short8*)(&lr[row * 136 + kbase]);
}

// ---------------- fused MLP: eps = (gelu(z@W1 + b1 + t*tw))@W2 + b2 --------
// Block: 512 thr (8 waves), M=32 rows (16 b x 2 l, row = il*16 + b), grid 512.
// z is split ONCE into LDS (phase 1); GEMM1 runs per half-H (acc1[4] live),
// each half feeding 2 quarter phases (h split -> LDS -> GEMM2 partial-K).
// Peak live regs ~100 -> no scratch spill (R5 spilled acc1[16]: 33 MB/dispatch
// HBM writeback, 60us mlp).
__global__ __launch_bounds__(512, 2) void mlp_kernel(
    const float* __restrict__ z, const float* __restrict__ y,
    const float* __restrict__ mk,
    const unsigned short* __restrict__ W1h, const unsigned short* __restrict__ W1m,
    const unsigned short* __restrict__ W1l, const unsigned short* __restrict__ W2h,
    const unsigned short* __restrict__ W2m, const unsigned short* __restrict__ W2l,
    const float* __restrict__ b1, const float* __restrict__ tw,
    const float* __restrict__ b2, float t_feat,
    float* __restrict__ eps_out, float* __restrict__ ent,
    float* __restrict__ accum) {
    __shared__ unsigned z_hm[32 * 132];        // z: h|m packed
    __shared__ unsigned short z_l[32 * 136];   // z: l
    __shared__ unsigned h_hm[32 * 132];        // h quarter: h|m packed
    __shared__ unsigned short h_l[32 * 136];   // h quarter: l
    __shared__ float red1[8], red2[8];
    const int tid = threadIdx.x;
    const int w = tid >> 6, lane = tid & 63;
    const int quad = lane >> 4, m16 = lane & 15;
    const int l0 = blockIdx.x * 2;

    // ---- phase 1: stage split z into LDS (each element exactly once) ----
#pragma unroll
    for (int e = 0; e < 2; ++e) {
        const int f = tid * 8 + e * 4;  // 0..4095
        const int r = f >> 7, c = f & 127;
        const int b = r & 15, il = r >> 4;
        const float4 v = *(const float4*)(z + ((size_t)b * 1024 + l0 + il) * 128 + c);
        const float xs[4] = {v.x, v.y, v.z, v.w};
#pragma unroll
        for (int i = 0; i < 4; ++i) {
            unsigned uh, um, ul;
            split3(xs[i], uh, um, ul);
            z_hm[r * 132 + c + i] = (uh >> 16) | (um & 0xffff0000u);
            z_l[r * 136 + c + i] = (unsigned short)(ul >> 16);
        }
    }
    __syncthreads();

    floatx4 acc2[2];  // eps tiles: il 0,1; this wave's nt2 = w
    acc2[0] = (floatx4){0.f, 0.f, 0.f, 0.f};
    acc2[1] = (floatx4){0.f, 0.f, 0.f, 0.f};

    for (int hf = 0; hf < 2; ++hf) {
        // ---- GEMM1 half: quarters q=2hf, 2hf+1; wave's nt1 = q*8 + w ----
        floatx4 acc1[4];  // [s*2 + il]
#pragma unroll
        for (int i = 0; i < 4; ++i) acc1[i] = (floatx4){0.f, 0.f, 0.f, 0.f};

#pragma unroll
        for (int kt = 0; kt < 4; ++kt) {
            short8 Ah[2], Am[2], Al[2];
#pragma unroll
            for (int il = 0; il < 2; ++il)
                ldsA(z_hm, z_l, il * 16 + m16, kt * 32 + quad * 8,
                     Ah[il], Am[il], Al[il]);
#pragma unroll
            for (int s = 0; s < 2; ++s) {
                const int nt1 = (hf * 2 + s) * 8 + w;
                const size_t off = ((size_t)(kt * 32 + nt1) * 64 + lane) * 8;
                const short8 bh = *(const short8*)(W1h + off);
                const short8 bm = *(const short8*)(W1m + off);
                const short8 bl = *(const short8*)(W1l + off);
#pragma unroll
                for (int il = 0; il < 2; ++il) {
                    floatx4 a = acc1[s * 2 + il];
                    MFMA6(Ah[il], Am[il], Al[il], bh, bm, bl, a);
                    acc1[s * 2 + il] = a;
                }
            }
        }

        // ---- quarter phases: gelu+split h -> LDS, GEMM2 partial-K ----
#pragma unroll
        for (int s = 0; s < 2; ++s) {
            const int q = hf * 2 + s;
            __syncthreads();  // previous quarter's h-LDS reads done
            {
                const int coll = w * 16 + m16;     // quarter-local col
                const int colg = q * 128 + coll;   // global H col
                const float bb = b1[colg] + t_feat * tw[colg];
#pragma unroll
                for (int il = 0; il < 2; ++il) {
#pragma unroll
                    for (int r = 0; r < 4; ++r) {
                        const float x = gelu_fast(acc1[s * 2 + il][r] + bb);
                        unsigned uh, um, ul;
                        split3(x, uh, um, ul);
                        const int row = il * 16 + quad * 4 + r;
                        h_hm[row * 132 + coll] = (uh >> 16) | (um & 0xffff0000u);
                        h_l[row * 136 + coll] = (unsigned short)(ul >> 16);
                    }
                }
            }
            __syncthreads();

#pragma unroll
            for (int ktl = 0; ktl < 4; ++ktl) {
                short8 Ah2[2], Am2[2], Al2[2];
#pragma unroll
                for (int il = 0; il < 2; ++il)
                    ldsA(h_hm, h_l, il * 16 + m16, ktl * 32 + quad * 8,
                         Ah2[il], Am2[il], Al2[il]);
                const int ktg = q * 4 + ktl;
                const size_t off = ((size_t)(ktg * 8 + w) * 64 + lane) * 8;
                const short8 bh = *(const short8*)(W2h + off);
                const short8 bm = *(const short8*)(W2m + off);
                const short8 bl = *(const short8*)(W2l + off);
#pragma unroll
                for (int il = 0; il < 2; ++il) {
                    floatx4 a = acc2[il];
                    MFMA6(Ah2[il], Am2[il], Al2[il], bh, bm, bl, a);
                    acc2[il] = a;
                }
            }
        }
    }

    // ---- epilogue: +b2, write eps, ent = mean_b |eps| ----
    {
        const int col = w * 16 + m16;  // nt2 = w
        const float bb2 = b2[col];
#pragma unroll
        for (int il = 0; il < 2; ++il) {
            float pa = 0.f;
#pragma unroll
            for (int r = 0; r < 4; ++r) {
                const float e = acc2[il][r] + bb2;
                const int b = quad * 4 + r;
                eps_out[((size_t)b * 1024 + l0 + il) * 128 + col] = e;
                pa += fabsf(e);
            }
            pa += __shfl_xor(pa, 16);
            pa += __shfl_xor(pa, 32);
            if (quad == 0) ent[(l0 + il) * 128 + col] = pa * (1.0f / 16.0f);
        }
    }

    // ---- obs_err stats over this block's 32 rows ----
    float s1 = 0.f, s2 = 0.f;
#pragma unroll
    for (int e = 0; e < 2; ++e) {
        const int f = tid * 8 + e * 4;
        const int r = f >> 7, c = f & 127;
        const int b = r & 15, il = r >> 4;
        const size_t g = ((size_t)b * 1024 + l0 + il) * 128 + c;
        const float4 zv = *(const float4*)(z + g);
        const float4 yv = *(const float4*)(y + g);
        const float4 mv = *(const float4*)(mk + g);
        float oe;
        oe = (zv.x - yv.x) * mv.x; s1 += oe; s2 += oe * oe;
        oe = (zv.y - yv.y) * mv.y; s1 += oe; s2 += oe * oe;
        oe = (zv.z - yv.z) * mv.z; s1 += oe; s2 += oe * oe;
        oe = (zv.w - yv.w) * mv.w; s1 += oe; s2 += oe * oe;
    }
#pragma unroll
    for (int off = 32; off; off >>= 1) {
        s1 += __shfl_down(s1, off);
        s2 += __shfl_down(s2, off);
    }
    if (lane == 0) { red1[w] = s1; red2[w] = s2; }
    __syncthreads();
    if (tid == 0) {
        float a1 = 0.f, a2 = 0.f;
#pragma unroll
        for (int i = 0; i < 8; ++i) { a1 += red1[i]; a2 += red2[i]; }
        atomicAdd(&accum[0], a1);
        atomicAdd(&accum[1], a2);
    }
}

// ---------------- multiscale pooling (w = 2,4,8 from ent) ------------------
__global__ __launch_bounds__(256) void pool_kernel(
    const float* __restrict__ ent, float* __restrict__ p1,
    float* __restrict__ p2, float* __restrict__ p3) {
    const int idx = blockIdx.x * 256 + threadIdx.x;  // < 43008
    if (idx < 32768) {  // w=2: 512 x 64
        const int r = idx >> 6, c = idx & 63;
        float s = 0.f;
#pragma unroll
        for (int i = 0; i < 2; ++i)
#pragma unroll
            for (int j = 0; j < 2; ++j) s += ent[((r * 2 + i) << 7) + c * 2 + j];
        p1[idx] = s * 0.25f;
    } else if (idx < 40960) {  // w=4: 256 x 32
        const int t = idx - 32768;
        const int r = t >> 5, c = t & 31;
        float s = 0.f;
#pragma unroll
        for (int i = 0; i < 4; ++i)
#pragma unroll
            for (int j = 0; j < 4; ++j) s += ent[((r * 4 + i) << 7) + c * 4 + j];
        p2[t] = s * 0.0625f;
    } else {  // w=8: 128 x 16
        const int t = idx - 40960;
        const int r = t >> 4, c = t & 15;
        float s = 0.f;
#pragma unroll
        for (int i = 0; i < 8; ++i)
#pragma unroll
            for (int j = 0; j < 8; ++j) s += ent[((r * 8 + i) << 7) + c * 8 + j];
        p3[t] = s * (1.0f / 64.0f);
    }
}

// ------- radix-select histogram pass + embedded last-block scan ------------
// 85 blocks: scale0=[0,64), scale1=[64,80), scale2=[80,84), scale3=84.
// After per-block hist atomics, the LAST block to finish (device atomic ctr)
// performs the 256-bin suffix scan for all 4 scales, updates gprefix/gkrem,
// and zeroes ghist for the next pass. Correct under any dispatch order.
__global__ __launch_bounds__(256) void hist_kernel(
    const float* __restrict__ e0, const float* __restrict__ e1,
    const float* __restrict__ e2, const float* __restrict__ e3,
    unsigned* __restrict__ ghist, unsigned* __restrict__ gprefix,
    unsigned* __restrict__ gkrem, unsigned* __restrict__ dctr, int shift) {
    const int bid = blockIdx.x;
    const float* data;
    int scale, base;
    if (bid < 64) { scale = 0; data = e0; base = bid * 2048; }
    else if (bid < 80) { scale = 1; data = e1; base = (bid - 64) * 2048; }
    else if (bid < 84) { scale = 2; data = e2; base = (bid - 80) * 2048; }
    else { scale = 3; data = e3; base = 0; }

    __shared__ unsigned hist[4][256];
    __shared__ unsigned sh[256];
    __shared__ bool sh_last;
    const int t = threadIdx.x;
    const int w = t >> 6;
#pragma unroll
    for (int i = t; i < 1024; i += 256) ((unsigned*)hist)[i] = 0u;
    __syncthreads();

    const unsigned prefix = gprefix[scale];  // pass 0: hmask==0, value unused
    const unsigned hmask = (shift == 24) ? 0u : (0xFFFFFFFFu << (shift + 8));

#pragma unroll
    for (int i = t; i < 2048; i += 256) {
        const unsigned u = ford(data[base + i]);
        if ((u & hmask) == (prefix & hmask))
            atomicAdd(&hist[w][(u >> shift) & 255u], 1u);
    }
    __syncthreads();
    const unsigned c = hist[0][t] + hist[1][t] + hist[2][t] + hist[3][t];
    if (c) atomicAdd(&ghist[scale * 256 + t], c);
    __syncthreads();  // drains this block's atomics (vmcnt(0) before barrier)

    if (t == 0) {
        __threadfence();
        sh_last = (atomicAdd(dctr, 1u) == 84u);
    }
    __syncthreads();
    if (!sh_last) return;

    // ---- last block: scan all 4 scales ----
    __threadfence();
    const unsigned Kc[4] = {26214u, 6553u, 1638u, 409u};
#pragma unroll
    for (int s = 0; s < 4; ++s) {
        sh[t] = atomicAdd(&ghist[s * 256 + t], 0u);  // coherent load
        __syncthreads();
#pragma unroll
        for (int off = 1; off < 256; off <<= 1) {
            const unsigned v = (t + off < 256) ? sh[t + off] : 0u;
            __syncthreads();
            sh[t] += v;
            __syncthreads();
        }
        const unsigned suf = sh[t];
        const unsigned sufn = (t < 255) ? sh[t + 1] : 0u;
        const unsigned krem = (shift == 24) ? Kc[s] : gkrem[s];
        const unsigned pref = (shift == 24) ? 0u : gprefix[s];
        if (suf >= krem && sufn < krem) {  // unique: suf non-increasing
            gprefix[s] = pref | ((unsigned)t << shift);
            gkrem[s] = krem - sufn;
        }
        ghist[s * 256 + t] = 0u;  // visible to next launch
        __syncthreads();
    }
}

// ---------------- fused update: guidance + scale-select + DPM step ---------
__global__ __launch_bounds__(256) void update_kernel(
    float* __restrict__ z, const float* __restrict__ y,
    const float* __restrict__ mk, const float* __restrict__ eps,
    const float* __restrict__ ent, const float* __restrict__ p1,
    const float* __restrict__ p2, const float* __restrict__ p3,
    const unsigned* __restrict__ thr, const float* __restrict__ accum,
    float base_a, float base_b, float h_lam) {
    const int idx = blockIdx.x * 256 + threadIdx.x;  // < BLC
    const int p = idx & (LC - 1);
    const int l = p >> 7;
    const int c = p & 127;

    const float mean = accum[0] * (1.0f / (float)BLC);
    const float var = accum[1] * (1.0f / (float)BLC) - mean * mean;

    const float zi = z[idx];
    const float oe = (zi - y[idx]) * mk[idx];
    const float guid = -oe / (var + 1e-8f);
    const float ei = eps[idx];

    float ent_v = 0.f;
    bool sel = false;
    {
        const float v0 = ent[p];
        if (ford(v0) >= thr[0]) { ent_v = v0; sel = true; }
        else {
            const float v1 = p1[((l >> 1) << 6) + (c >> 1)];
            if (ford(v1) >= thr[1]) { ent_v = v1; sel = true; }
            else {
                const float v2 = p2[((l >> 2) << 5) + (c >> 2)];
                if (ford(v2) >= thr[2]) { ent_v = v2; sel = true; }
                else {
                    const float v3 = p3[((l >> 3) << 4) + (c >> 3)];
                    if (ford(v3) >= thr[3]) { ent_v = v3; sel = true; }
                }
            }
        }
    }
    if (sel) {
        float corr;
        if (ent_v > 0.5f)
            corr = 1.0f + h_lam + h_lam * h_lam * (1.0f / 3.0f);
        else if (ent_v > 0.1f)
            corr = 1.0f + 0.5f * h_lam;
        else
            corr = 1.0f;
        const float gs = 2.0f * ent_v / (ent_v + 1.0f);
        z[idx] = base_a * zi - base_b * (corr * ei) + gs * guid;
    }
}

// ---------------------------------------------------------------------------
extern "C" void kernel_launch(void* const* d_in, const int* in_sizes, int n_in,
                              void* d_out, int out_size, void* d_ws,
                              size_t ws_size, hipStream_t stream) {
    const float* y_obs = (const float*)d_in[0];
    const float* mask = (const float*)d_in[1];
    const float* z_init = (const float*)d_in[2];
    const float* W1 = (const float*)d_in[3];
    const float* b1 = (const float*)d_in[4];
    const float* W2 = (const float*)d_in[5];
    const float* b2 = (const float*)d_in[6];
    const float* tw = (const float*)d_in[7];
    float* z = (float*)d_out;
    float* ws = (float*)d_ws;

    // workspace layout (float offsets)
    float* eps = ws;                                 // 2097152
    float* ent = ws + 2097152;                       // 131072
    float* p1 = ws + 2228224;                        // 32768
    float* p2 = ws + 2260992;                        // 8192
    float* p3 = ws + 2269184;                        // 2048
    // zero-init block (single memset): ghist[1024] + done[16] + accum[8]
    unsigned* ghist = (unsigned*)(ws + 2271232);     // 1024 u32
    unsigned* done = (unsigned*)(ws + 2272256);      // 16 u32
    float* accum = ws + 2272272;                     // 8 f32
    unsigned* gprefix = (unsigned*)(ws + 2272280);   // 4
    unsigned* gkrem = (unsigned*)(ws + 2272284);     // 4
    unsigned short* W1h = (unsigned short*)(ws + 2272288);  // 65536 u16 each
    unsigned short* W1m = (unsigned short*)(ws + 2305056);
    unsigned short* W1l = (unsigned short*)(ws + 2337824);
    unsigned short* W2h = (unsigned short*)(ws + 2370592);
    unsigned short* W2m = (unsigned short*)(ws + 2403360);
    unsigned short* W2l = (unsigned short*)(ws + 2436128);

    // diffusion schedule in fp32 (input-independent)
    float alpha_[1000], sigma_[1000], lam_[1000];
    {
        float ac = 1.0f;
        for (int i = 0; i < 1000; ++i) {
            const float beta = 1e-4f + (0.02f - 1e-4f) * ((float)i / 999.0f);
            ac = ac * (1.0f - beta);
            alpha_[i] = sqrtf(ac);
            sigma_[i] = sqrtf(1.0f - ac);
            lam_[i] = logf(alpha_[i]) - logf(sigma_[i]);
        }
    }

    hipMemcpyAsync(z, z_init, sizeof(float) * BLC, hipMemcpyDeviceToDevice,
                   stream);
    hipMemsetAsync(ghist, 0, (1024 + 16 + 8) * sizeof(unsigned), stream);
    wsplit_kernel<<<512, 256, 0, stream>>>(W1, W2, W1h, W1m, W1l, W2h, W2m,
                                           W2l);

    for (int si = 0; si < 4; ++si) {
        const int k = 999 - si * 250;
        const int kp = (k - 250 > 0) ? (k - 250) : 0;
        const float t_feat = (float)k / 1000.0f;
        const float h_lam = lam_[kp] - lam_[k];
        const float base_a = alpha_[kp] / alpha_[k];
        const float base_b = sigma_[kp] * (expf(h_lam) - 1.0f);

        mlp_kernel<<<512, 512, 0, stream>>>(
            z, y_obs, mask, W1h, W1m, W1l, W2h, W2m, W2l, b1, tw, b2, t_feat,
            eps, ent, accum + 2 * si);
        pool_kernel<<<168, 256, 0, stream>>>(ent, p1, p2, p3);
        int pass = 0;
        for (int shift = 24; shift >= 0; shift -= 8, ++pass) {
            hist_kernel<<<85, 256, 0, stream>>>(ent, p1, p2, p3, ghist,
                                                gprefix, gkrem,
                                                done + si * 4 + pass, shift);
        }
        update_kernel<<<8192, 256, 0, stream>>>(z, y_obs, mask, eps, ent, p1,
                                                p2, p3, gprefix, accum + 2 * si,
                                                base_a, base_b, h_lam);
    }
}